// Round 1
// baseline (12335.670 us; speedup 1.0000x reference)
//
#include <hip/hip_runtime.h>
#include <hip/hip_bf16.h>

#define SEQ 300
#define BAT 250
#define UNITS 1024
#define EMBD 100
#define MP 256            // padded batch rows for MFMA tiles
#define MROWS (SEQ*BAT)   // 75000 (s-major: row = s*250 + b)

typedef __bf16 bf16;
typedef __bf16 bf16x8 __attribute__((ext_vector_type(8)));
typedef float  f32x4  __attribute__((ext_vector_type(4)));

// scratch as device globals (avoids ws_size dependence)
__device__ __align__(16) bf16 g_xp0[(size_t)MROWS * UNITS + 8192]; // [s][b][u] bf16 (+tail guard for pad rows)
__device__ __align__(16) bf16 g_Wh0T[UNITS * UNITS];               // [n][k]
__device__ __align__(16) bf16 g_Wx1T[UNITS * UNITS];
__device__ __align__(16) bf16 g_Wh1T[UNITS * UNITS];
__device__ __align__(16) bf16 g_h0[2][MP * UNITS];                 // ping-pong h0 state
__device__ __align__(16) bf16 g_h1[2][MP * UNITS];                 // ping-pong h1 state

// ---------------- prep: transpose-convert weights to bf16 [N][K]; zero h state ----------------
__global__ __launch_bounds__(256) void prep_kernel(const float* __restrict__ Wh0,
                                                   const float* __restrict__ Wx1,
                                                   const float* __restrict__ Wh1) {
  int bx = blockIdx.x, tid = threadIdx.x;
  if (bx < 768) {
    const float* W  = (bx < 256) ? Wh0   : (bx < 512 ? Wx1   : Wh1);
    bf16*        WT = (bx < 256) ? g_Wh0T : (bx < 512 ? g_Wx1T : g_Wh1T);
    int tile = bx & 255;
    int kt = tile & 15, nt = tile >> 4;   // 16x16 tiles of 64x64
    __shared__ bf16 T[64][72];
    #pragma unroll
    for (int p = 0; p < 16; ++p) {
      int idx = tid + p * 256;
      int r = idx >> 6, c = idx & 63;
      T[r][c] = (bf16)W[(size_t)(kt * 64 + r) * UNITS + nt * 64 + c]; // coalesced read
    }
    __syncthreads();
    #pragma unroll
    for (int p = 0; p < 16; ++p) {
      int idx = tid + p * 256;
      int r = idx >> 6, c = idx & 63;
      WT[(size_t)(nt * 64 + r) * UNITS + kt * 64 + c] = T[c][r];     // coalesced write
    }
  } else {
    int zb = bx - 768;  // 64 zeroing blocks
    bf16 z = (bf16)0.0f;
    for (int i = zb * 256 + tid; i < 2 * MP * UNITS; i += 64 * 256) {
      ((bf16*)g_h0)[i] = z;
      ((bf16*)g_h1)[i] = z;
    }
  }
}

// ---------------- phase A: xp0[s*250+b][u] = emb[tokens[b][s]] @ Wx0 + b0 (fp32, out bf16) ----------------
__global__ __launch_bounds__(256) void xp0_kernel(const int* __restrict__ tokens,
                                                  const float* __restrict__ emb,
                                                  const float* __restrict__ Wx0,
                                                  const float* __restrict__ b0) {
  __shared__ float A[32][104];          // 32 gathered embedding rows (K=100, pad 104)
  int tid = threadIdx.x;
  int mt = blockIdx.x;                  // 0..2343  (32 rows each)
  int nt = blockIdx.y;                  // 0..3     (256 cols each)

  for (int idx = tid; idx < 3200; idx += 256) {
    int r = idx / 100, e = idx - r * 100;
    int R = mt * 32 + r;
    int tok = 0;
    if (R < MROWS) { int b = R % BAT; int s = R / BAT; tok = tokens[b * SEQ + s]; }
    A[r][e] = emb[(size_t)tok * EMBD + e];
  }
  __syncthreads();

  int c0 = nt * 256 + (tid & 63);       // cols c0 + {0,64,128,192}
  int r0 = (tid >> 6) * 8;              // rows r0..r0+7
  float acc[8][4];
  #pragma unroll
  for (int i = 0; i < 8; ++i)
    #pragma unroll
    for (int j = 0; j < 4; ++j) acc[i][j] = 0.f;

  for (int e = 0; e < EMBD; ++e) {
    const float* wr = Wx0 + (size_t)e * UNITS + c0;
    float w0 = wr[0], w1 = wr[64], w2 = wr[128], w3 = wr[192];
    #pragma unroll
    for (int i = 0; i < 8; ++i) {
      float x = A[r0 + i][e];           // wave-uniform broadcast
      acc[i][0] += x * w0; acc[i][1] += x * w1; acc[i][2] += x * w2; acc[i][3] += x * w3;
    }
  }
  float bb0 = b0[c0], bb1 = b0[c0 + 64], bb2 = b0[c0 + 128], bb3 = b0[c0 + 192];
  #pragma unroll
  for (int i = 0; i < 8; ++i) {
    int R = mt * 32 + r0 + i;
    if (R < MROWS) {
      bf16* dst = g_xp0 + (size_t)R * UNITS + c0;
      dst[0]   = (bf16)(acc[i][0] + bb0);
      dst[64]  = (bf16)(acc[i][1] + bb1);
      dst[128] = (bf16)(acc[i][2] + bb2);
      dst[192] = (bf16)(acc[i][3] + bb3);
    }
  }
}

// ---------------- per-step pipelined kernel: blocks 0..63 -> h0[t], blocks 64..127 -> h1[t-1] ----------------
__global__ __launch_bounds__(256) void step_kernel(int t, const float* __restrict__ b1) {
  int bx = blockIdx.x;
  int layer = bx >> 6;
  if (layer == 0 && t == SEQ) return;   // no layer0 work on final launch
  if (layer == 1 && t == 0) return;     // no layer1 work on first launch
  int tile = bx & 63;
  int mt = tile & 3;                    // M tile (x64)
  int ntile = tile >> 2;                // N tile (x64), 0..15
  int tid = threadIdx.x;
  int w = tid >> 6;                     // wave 0..3 -> 16-row strip
  int lane = tid & 63;

  __shared__ __align__(16) bf16 Asub[64 * 72];
  __shared__ __align__(16) bf16 Bsub[64 * 72];

  const bf16 *A1, *A2 = nullptr, *Bw1, *Bw2 = nullptr;
  bf16* dst;
  int niter;
  if (layer == 0) {
    A1 = g_h0[(t + 1) & 1]; Bw1 = g_Wh0T;       // h0[t-1] @ Wh0
    dst = g_h0[t & 1];
    niter = 16;
  } else {
    A1 = g_h0[(t - 1) & 1]; Bw1 = g_Wx1T;       // h0[t-1] @ Wx1
    A2 = g_h1[t & 1];       Bw2 = g_Wh1T;       // h1[t-2] @ Wh1
    dst = g_h1[(t - 1) & 1];
    niter = 32;
  }

  f32x4 acc[4];
  f32x4 z = {0.f, 0.f, 0.f, 0.f};
  #pragma unroll
  for (int nf = 0; nf < 4; ++nf) acc[nf] = z;

  int srow = tid >> 3;                  // 0..31
  int scol = (tid & 7) * 8;             // bf16 col offset, 16B chunks

  for (int it = 0; it < niter; ++it) {
    const bf16* Asrc = (it < 16) ? A1 : A2;
    const bf16* Bsrc = (it < 16) ? Bw1 : Bw2;
    int kc = (it & 15) * 64;
    __syncthreads();                    // protect LDS from previous iter's readers
    *(bf16x8*)&Asub[srow * 72 + scol]        = *(const bf16x8*)&Asrc[(size_t)(mt * 64 + srow) * UNITS + kc + scol];
    *(bf16x8*)&Asub[(srow + 32) * 72 + scol] = *(const bf16x8*)&Asrc[(size_t)(mt * 64 + srow + 32) * UNITS + kc + scol];
    *(bf16x8*)&Bsub[srow * 72 + scol]        = *(const bf16x8*)&Bsrc[(size_t)(ntile * 64 + srow) * UNITS + kc + scol];
    *(bf16x8*)&Bsub[(srow + 32) * 72 + scol] = *(const bf16x8*)&Bsrc[(size_t)(ntile * 64 + srow + 32) * UNITS + kc + scol];
    __syncthreads();

    int arow = 16 * w + (lane & 15);
    int koff = (lane >> 4) * 8;
    bf16x8 a0 = *(const bf16x8*)&Asub[arow * 72 + koff];       // k 0..31 slice
    bf16x8 a1 = *(const bf16x8*)&Asub[arow * 72 + 32 + koff];  // k 32..63 slice
    #pragma unroll
    for (int nf = 0; nf < 4; ++nf) {
      int brow = nf * 16 + (lane & 15);
      bf16x8 bv0 = *(const bf16x8*)&Bsub[brow * 72 + koff];
      bf16x8 bv1 = *(const bf16x8*)&Bsub[brow * 72 + 32 + koff];
      acc[nf] = __builtin_amdgcn_mfma_f32_16x16x32_bf16(a0, bv0, acc[nf], 0, 0, 0);
      acc[nf] = __builtin_amdgcn_mfma_f32_16x16x32_bf16(a1, bv1, acc[nf], 0, 0, 0);
    }
  }

  // epilogue: C row = (lane>>4)*4 + reg, col = lane&15 (m89-verified mapping)
  int rbase = mt * 64 + 16 * w + ((lane >> 4) * 4);
  int cbase = ntile * 64 + (lane & 15);
  #pragma unroll
  for (int nf = 0; nf < 4; ++nf) {
    int gcol = cbase + nf * 16;
    float badd = (layer == 1) ? b1[gcol] : 0.f;
    #pragma unroll
    for (int reg = 0; reg < 4; ++reg) {
      int grow = rbase + reg;
      float v = acc[nf][reg];
      if (layer == 0) {
        v += (float)g_xp0[(size_t)t * BAT * UNITS + (size_t)grow * UNITS + gcol]; // pad rows read guard tail: harmless
      } else {
        v += badd;
      }
      dst[(size_t)grow * UNITS + gcol] = (bf16)tanhf(v);
    }
  }
}

// ---------------- logits: sigmoid(h1_final @ Wo + bo) ----------------
__global__ __launch_bounds__(64) void logits_kernel(const float* __restrict__ Wo,
                                                    const float* __restrict__ bo,
                                                    float* __restrict__ out) {
  int b = blockIdx.x;
  int lane = threadIdx.x;
  const bf16* h = g_h1[(SEQ - 1) & 1] + (size_t)b * UNITS;  // h1[299] lives in buffer 1
  float s = 0.f;
  for (int u = lane; u < UNITS; u += 64) s += (float)h[u] * Wo[u];
  #pragma unroll
  for (int off = 32; off; off >>= 1) s += __shfl_xor(s, off, 64);
  if (lane == 0) out[b] = 1.f / (1.f + expf(-(s + bo[0])));
}

extern "C" void kernel_launch(void* const* d_in, const int* in_sizes, int n_in,
                              void* d_out, int out_size, void* d_ws, size_t ws_size,
                              hipStream_t stream) {
  const int*   tokens = (const int*)  d_in[0];
  const float* emb    = (const float*)d_in[1];
  const float* Wx0    = (const float*)d_in[2];
  const float* Wh0    = (const float*)d_in[3];
  const float* b0     = (const float*)d_in[4];
  const float* Wx1    = (const float*)d_in[5];
  const float* Wh1    = (const float*)d_in[6];
  const float* b1     = (const float*)d_in[7];
  const float* Wo     = (const float*)d_in[8];
  const float* bo     = (const float*)d_in[9];
  float* out = (float*)d_out;

  prep_kernel<<<832, 256, 0, stream>>>(Wh0, Wx1, Wh1);

  dim3 gx((MROWS + 31) / 32, 4);
  xp0_kernel<<<gx, 256, 0, stream>>>(tokens, emb, Wx0, b0);

  for (int t = 0; t <= SEQ; ++t)
    step_kernel<<<128, 256, 0, stream>>>(t, b1);

  logits_kernel<<<250, 64, 0, stream>>>(Wo, bo, out);
}

// Round 2
// 8493.133 us; speedup vs baseline: 1.4524x; 1.4524x over previous
//
#include <hip/hip_runtime.h>
#include <hip/hip_bf16.h>

#define SEQ 300
#define BAT 250
#define UNITS 1024
#define EMBD 100
#define MROWS (SEQ*BAT)   // 75000, s-major: row = s*250 + b

typedef __bf16 bf16;
typedef __bf16 bf16x8 __attribute__((ext_vector_type(8)));
typedef float  f32x16 __attribute__((ext_vector_type(16)));

#define MFMA32(a,b,c) __builtin_amdgcn_mfma_f32_32x32x16_bf16(a, b, c, 0, 0, 0)
#define F32X16_ZERO {0.f,0.f,0.f,0.f,0.f,0.f,0.f,0.f,0.f,0.f,0.f,0.f,0.f,0.f,0.f,0.f}

// ---- device globals (zero-init at load; reset to initial state each call) ----
__device__ __align__(16) bf16  g_xp0[(size_t)MROWS * UNITS + 8192]; // [s*250+b][u], +guard rows (stay 0)
__device__ __align__(16) bf16  g_h0[2][256 * UNITS];                // ping-pong h0 (rows 250..255 pad)
__device__ __align__(16) bf16  g_h1[2][256 * UNITS];                // ping-pong h1
__device__ __align__(16) float g_P[64 * 4096];                      // FR->BK partial tiles (64x64 f32)
__device__ unsigned g_flag[64];                                     // FR->BK per-tile generation flags
__device__ unsigned g_cnt1[256];                                    // 8 counters, stride 32 (128B apart)
__device__ unsigned g_cnt2;
__device__ unsigned g_epoch;

__device__ __forceinline__ float tanh_fast(float x) {
  float e = __expf(2.f * x);
  return 1.f - 2.f / (e + 1.f);
}

// two-level accumulating grid barrier for 192 co-resident blocks (24 per group x 8)
__device__ __forceinline__ void grid_barrier(unsigned gen) {
  __syncthreads();
  if (threadIdx.x == 0) {
    __builtin_amdgcn_fence(__ATOMIC_RELEASE, "agent");
    const int g = (int)(blockIdx.x & 7);
    unsigned a = __hip_atomic_fetch_add(&g_cnt1[g * 32], 1u, __ATOMIC_RELAXED, __HIP_MEMORY_SCOPE_AGENT);
    if (a == gen * 24u - 1u) {
      unsigned b = __hip_atomic_fetch_add(&g_cnt2, 1u, __ATOMIC_RELAXED, __HIP_MEMORY_SCOPE_AGENT);
      if (b == gen * 8u - 1u) {
        __builtin_amdgcn_fence(__ATOMIC_ACQ_REL, "agent");
        __hip_atomic_store(&g_epoch, gen, __ATOMIC_RELAXED, __HIP_MEMORY_SCOPE_AGENT);
      }
    }
    while (__hip_atomic_load(&g_epoch, __ATOMIC_RELAXED, __HIP_MEMORY_SCOPE_AGENT) < gen)
      __builtin_amdgcn_s_sleep(1);
    __builtin_amdgcn_fence(__ATOMIC_ACQUIRE, "agent");
  }
  __syncthreads();
}

// ---------------- xp0 = emb[tokens] @ Wx0 + b0  (bf16 MFMA, K padded 100->128) ----------------
__global__ __launch_bounds__(256) void xp0_kernel(const int* __restrict__ tokens,
                                                  const float* __restrict__ emb,
                                                  const float* __restrict__ Wx0,
                                                  const float* __restrict__ b0) {
  __shared__ bf16 A[64 * 128];   // [64 rows][128 k], XOR-swizzled rows
  __shared__ int toks[64];
  const int mt = blockIdx.x;     // 64-row tiles: 1172
  const int nt = blockIdx.y;     // 256-col tiles: 4
  const int tid = threadIdx.x, lane = tid & 63, wv = tid >> 6;

  if (tid < 64) {
    int R = mt * 64 + tid;
    int tok = 0;
    if (R < MROWS) { int s = R / 250; int b = R - s * 250; tok = tokens[b * SEQ + s]; }
    toks[tid] = tok;
  }
  __syncthreads();
  for (int idx = tid; idx < 64 * 128; idx += 256) {
    int r = idx >> 7, k = idx & 127;
    float v = (k < EMBD) ? emb[(size_t)toks[r] * EMBD + k] : 0.f;
    unsigned off = (unsigned)(r * 256 + k * 2);
    off ^= (unsigned)((r & 7) << 4);
    *(bf16*)((char*)A + off) = (bf16)v;
  }

  // B fragments from Wx0 [k][1024] fp32 (k >= 100 -> 0)
  const int colb = nt * 256 + (wv << 6) + (lane & 31);
  bf16x8 Bf[2][8];
  #pragma unroll
  for (int nf = 0; nf < 2; ++nf) {
    #pragma unroll
    for (int kk = 0; kk < 8; ++kk) {
      const int kb = (kk << 4) + ((lane >> 5) << 3);
      bf16x8 f;
      #pragma unroll
      for (int j = 0; j < 8; ++j) {
        int k = kb + j;
        f[j] = (bf16)((k < EMBD) ? Wx0[(size_t)k * UNITS + colb + (nf << 5)] : 0.f);
      }
      Bf[nf][kk] = f;
    }
  }
  __syncthreads();

  f32x16 acc00 = F32X16_ZERO, acc01 = F32X16_ZERO, acc10 = F32X16_ZERO, acc11 = F32X16_ZERO;
  #pragma unroll
  for (int kk = 0; kk < 8; ++kk) {
    #pragma unroll
    for (int mf = 0; mf < 2; ++mf) {
      int row = (mf << 5) + (lane & 31);
      unsigned off = (unsigned)(row * 256 + ((kk << 4) + ((lane >> 5) << 3)) * 2);
      off ^= (unsigned)((row & 7) << 4);
      bf16x8 a = *(const bf16x8*)((const char*)A + off);
      if (mf == 0) { acc00 = MFMA32(a, Bf[0][kk], acc00); acc01 = MFMA32(a, Bf[1][kk], acc01); }
      else         { acc10 = MFMA32(a, Bf[0][kk], acc10); acc11 = MFMA32(a, Bf[1][kk], acc11); }
    }
  }

  const float bb0 = b0[colb], bb1 = b0[colb + 32];
  #pragma unroll
  for (int mf = 0; mf < 2; ++mf) {
    #pragma unroll
    for (int nf = 0; nf < 2; ++nf) {
      #pragma unroll
      for (int reg = 0; reg < 16; ++reg) {
        int r32 = (mf << 5) + ((lane >> 5) << 2) + (reg & 3) + ((reg >> 2) << 3);
        int R = mt * 64 + r32;
        if (R < MROWS) {
          float v = (mf == 0 ? (nf == 0 ? acc00[reg] : acc01[reg])
                             : (nf == 0 ? acc10[reg] : acc11[reg])) + (nf ? bb1 : bb0);
          g_xp0[(size_t)R * UNITS + nt * 256 + (wv << 6) + (nf << 5) + (lane & 31)] = (bf16)v;
        }
      }
    }
  }
}

// ---------------- persistent RNN scan: 192 blocks (64 L0, 64 FR, 64 BK), weights in registers ----------------
__global__ __launch_bounds__(512, 2) void rnn_persistent(const float* __restrict__ Wh0,
                                                         const float* __restrict__ Wx1,
                                                         const float* __restrict__ Wh1,
                                                         const float* __restrict__ b1) {
  const int bx = blockIdx.x;
  const int tid = threadIdx.x;
  const int lane = tid & 63;
  const int w = tid >> 6;             // 0..7
  const int mt = w & 1;               // M half (32 rows)
  const int kq = w >> 1;              // K quarter (256)
  const int role = bx >> 6;           // 0 = L0, 1 = FR (h0@Wx1), 2 = BK (h1@Wh1 + P)
  const int tile = bx & 63;
  const int tm = (tile >> 4) << 6;    // row base 0/64/128/192
  const int tn = (tile & 15) << 6;    // col base 0..960

  __shared__ float red[3][2][32][64]; // [kq-1][mt][nf*16+reg][lane] : 48KB

  const float* W = (role == 0) ? Wh0 : (role == 1) ? Wx1 : Wh1;

  // ---- one-time: weight fragments to registers (128 VGPRs) ----
  bf16x8 Bf[2][16];
  {
    const int n = tn + (lane & 31);
    const int kbase = (kq << 8) + ((lane >> 5) << 3);
    #pragma unroll
    for (int nf = 0; nf < 2; ++nf) {
      #pragma unroll
      for (int kk = 0; kk < 16; ++kk) {
        const float* src = W + (size_t)(kbase + (kk << 4)) * UNITS + n + (nf << 5);
        bf16x8 f;
        #pragma unroll
        for (int j = 0; j < 8; ++j) f[j] = (bf16)src[(size_t)j * UNITS];
        Bf[nf][kk] = f;
      }
    }
  }
  // b1 cached (BK only uses it)
  float b1v0 = 0.f, b1v1 = 0.f;
  if (role == 2) { b1v0 = b1[tn + (lane & 31)]; b1v1 = b1[tn + 32 + (lane & 31)]; }

  // ---- zero h state (2MB total) ----
  {
    int4 z = {0, 0, 0, 0};
    for (int i = bx * 512 + tid; i < 65536; i += 192 * 512) {
      ((int4*)g_h0)[i] = z;
      ((int4*)g_h1)[i] = z;
    }
  }
  grid_barrier(1u);

  for (int t = 0; t <= SEQ; ++t) {
    const bool active = (role == 0) ? (t < SEQ) : (t >= 1);
    if (active) {
      // A source: L0/FR read h0[t-1]; BK reads h1[t-2]
      const bf16* Asrc = (role == 2) ? g_h1[t & 1] : g_h0[(t + 1) & 1];

      // L0 epilogue prefetch: xp0[t] fragment values (independent of h)
      float xpre[32];
      if (role == 0 && kq == 0) {
        const bf16* xb = g_xp0 + (size_t)(t * BAT + tm + (mt << 5)) * UNITS + tn + (lane & 31);
        #pragma unroll
        for (int nf = 0; nf < 2; ++nf) {
          #pragma unroll
          for (int reg = 0; reg < 16; ++reg) {
            int r = ((lane >> 5) << 2) + (reg & 3) + ((reg >> 2) << 3);
            xpre[(nf << 4) + reg] = (float)xb[(size_t)r * UNITS + (nf << 5)];
          }
        }
      }

      // ---- GEMM: 16 k-steps, B in registers, A streamed from global ----
      const bf16* Ap = Asrc + (size_t)(tm + (mt << 5) + (lane & 31)) * UNITS + (kq << 8) + ((lane >> 5) << 3);
      f32x16 acc0 = F32X16_ZERO, acc1 = F32X16_ZERO;
      #pragma unroll
      for (int kk = 0; kk < 16; ++kk) {
        bf16x8 a = *(const bf16x8*)(Ap + (kk << 4));
        acc0 = MFMA32(a, Bf[0][kk], acc0);
        acc1 = MFMA32(a, Bf[1][kk], acc1);
      }

      // ---- K-partial exchange ----
      if (kq != 0) {
        #pragma unroll
        for (int reg = 0; reg < 16; ++reg) {
          red[kq - 1][mt][reg][lane]      = acc0[reg];
          red[kq - 1][mt][16 + reg][lane] = acc1[reg];
        }
      }
      __syncthreads();

      float f0[16], f1[16];
      if (kq == 0) {
        #pragma unroll
        for (int reg = 0; reg < 16; ++reg) {
          f0[reg] = acc0[reg] + red[0][mt][reg][lane]      + red[1][mt][reg][lane]      + red[2][mt][reg][lane];
          f1[reg] = acc1[reg] + red[0][mt][16 + reg][lane] + red[1][mt][16 + reg][lane] + red[2][mt][16 + reg][lane];
        }
      }

      if (role == 0) {
        if (kq == 0) {
          bf16* dst = g_h0[t & 1];
          #pragma unroll
          for (int nf = 0; nf < 2; ++nf) {
            #pragma unroll
            for (int reg = 0; reg < 16; ++reg) {
              int r32 = (mt << 5) + ((lane >> 5) << 2) + (reg & 3) + ((reg >> 2) << 3);
              int c = tn + (nf << 5) + (lane & 31);
              float v = (nf ? f1[reg] : f0[reg]) + xpre[(nf << 4) + reg];
              dst[(size_t)(tm + r32) * UNITS + c] = (bf16)tanh_fast(v);
            }
          }
        }
      } else if (role == 1) {
        if (kq == 0) {
          float* P = g_P + (size_t)tile * 4096;
          #pragma unroll
          for (int nf = 0; nf < 2; ++nf) {
            #pragma unroll
            for (int reg = 0; reg < 16; ++reg) {
              int r32 = (mt << 5) + ((lane >> 5) << 2) + (reg & 3) + ((reg >> 2) << 3);
              int c64 = (nf << 5) + (lane & 31);
              P[r32 * 64 + c64] = (nf ? f1[reg] : f0[reg]);
            }
          }
        }
        __syncthreads();   // P stores drained (vmcnt) by all waves
        if (tid == 0) {
          __builtin_amdgcn_fence(__ATOMIC_RELEASE, "agent");
          __hip_atomic_store(&g_flag[tile], (unsigned)t, __ATOMIC_RELAXED, __HIP_MEMORY_SCOPE_AGENT);
        }
      } else {
        if (tid == 0) {
          while (__hip_atomic_load(&g_flag[tile], __ATOMIC_RELAXED, __HIP_MEMORY_SCOPE_AGENT) < (unsigned)t)
            __builtin_amdgcn_s_sleep(1);
          __builtin_amdgcn_fence(__ATOMIC_ACQUIRE, "agent");
        }
        __syncthreads();
        if (kq == 0) {
          const float* P = g_P + (size_t)tile * 4096;
          bf16* dst = g_h1[(t + 1) & 1];   // h1[t-1]
          #pragma unroll
          for (int nf = 0; nf < 2; ++nf) {
            #pragma unroll
            for (int reg = 0; reg < 16; ++reg) {
              int r32 = (mt << 5) + ((lane >> 5) << 2) + (reg & 3) + ((reg >> 2) << 3);
              int c64 = (nf << 5) + (lane & 31);
              float v = (nf ? f1[reg] : f0[reg]) + P[r32 * 64 + c64] + (nf ? b1v1 : b1v0);
              dst[(size_t)(tm + r32) * UNITS + tn + c64] = (bf16)tanh_fast(v);
            }
          }
        }
      }
    }
    if (t < SEQ) grid_barrier((unsigned)(t + 2));
  }
}

// ---------------- logits + state reset for next call ----------------
__global__ __launch_bounds__(64) void logits_kernel(const float* __restrict__ Wo,
                                                    const float* __restrict__ bo,
                                                    float* __restrict__ out) {
  const int b = blockIdx.x;
  const int lane = threadIdx.x;
  if (b == 0) {  // reset barrier/flag state (persistent kernel fully done: stream order)
    if (lane < 64) g_flag[lane] = 0;
    if (lane < 8) g_cnt1[lane * 32] = 0;
    if (lane == 8) g_cnt2 = 0;
    if (lane == 9) g_epoch = 0;
  }
  const bf16* h = g_h1[1] + (size_t)b * UNITS;   // h1[299]
  float s = 0.f;
  for (int u = lane; u < UNITS; u += 64) s += (float)h[u] * Wo[u];
  #pragma unroll
  for (int off = 32; off; off >>= 1) s += __shfl_xor(s, off, 64);
  if (lane == 0) out[b] = 1.f / (1.f + __expf(-(s + bo[0])));
}

extern "C" void kernel_launch(void* const* d_in, const int* in_sizes, int n_in,
                              void* d_out, int out_size, void* d_ws, size_t ws_size,
                              hipStream_t stream) {
  const int*   tokens = (const int*)  d_in[0];
  const float* emb    = (const float*)d_in[1];
  const float* Wx0    = (const float*)d_in[2];
  const float* Wh0    = (const float*)d_in[3];
  const float* b0     = (const float*)d_in[4];
  const float* Wx1    = (const float*)d_in[5];
  const float* Wh1    = (const float*)d_in[6];
  const float* b1     = (const float*)d_in[7];
  const float* Wo     = (const float*)d_in[8];
  const float* bo     = (const float*)d_in[9];
  float* out = (float*)d_out;

  dim3 gx((MROWS + 63) / 64, 4);
  xp0_kernel<<<gx, 256, 0, stream>>>(tokens, emb, Wx0, b0);

  rnn_persistent<<<192, 512, 0, stream>>>(Wh0, Wx1, Wh1, b1);

  logits_kernel<<<BAT, 64, 0, stream>>>(Wo, bo, out);
}

// Round 3
// 7884.383 us; speedup vs baseline: 1.5646x; 1.0772x over previous
//
#include <hip/hip_runtime.h>
#include <hip/hip_bf16.h>

#define SEQ 300
#define BAT 250
#define UNITS 1024
#define EMBD 100
#define MROWS (SEQ*BAT)   // 75000, s-major: row = s*250 + b

typedef __bf16 bf16;
typedef __bf16 bf16x8 __attribute__((ext_vector_type(8)));
typedef float  f32x4  __attribute__((ext_vector_type(4)));
typedef float  f32x16 __attribute__((ext_vector_type(16)));

#define MFMA32(a,b,c) __builtin_amdgcn_mfma_f32_32x32x16_bf16(a,b,c,0,0,0)
#define F32X16_ZERO {0.f,0.f,0.f,0.f,0.f,0.f,0.f,0.f,0.f,0.f,0.f,0.f,0.f,0.f,0.f,0.f}

// ---- device globals ----
// xp0 plain row-major [R][1024]; h-state TILED: elem(r,u) -> ((r>>5)*128 + (u>>3))*256 + (r&31)*8 + (u&7)
__device__ __align__(16) bf16  g_xp0[(size_t)MROWS*UNITS + 8192];
__device__ __align__(16) bf16  g_h0[2][256*1024];
__device__ __align__(16) bf16  g_h1[2][256*1024];
__device__ __align__(16) float g_P[64][2][64*64];   // per (m,n) pair, double-buffered 64x64 f32
__device__ unsigned g_fh0[4], g_fh1[4], g_fP[64], g_fPc[64];

__device__ __forceinline__ float tanh_fast(float x) {
  float e = __expf(2.f * x);
  return 1.f - 2.f / (e + 1.f);
}
__device__ __forceinline__ unsigned aload(unsigned* p) {
  return __hip_atomic_load(p, __ATOMIC_RELAXED, __HIP_MEMORY_SCOPE_AGENT);
}
__device__ __forceinline__ void aadd(unsigned* p, unsigned v) {
  __hip_atomic_fetch_add(p, v, __ATOMIC_RELAXED, __HIP_MEMORY_SCOPE_AGENT);
}
__device__ __forceinline__ void astore(unsigned* p, unsigned v) {
  __hip_atomic_store(p, v, __ATOMIC_RELAXED, __HIP_MEMORY_SCOPE_AGENT);
}

// coalesced cache-bypass panel load: 16 x 1KB-per-wave contiguous dwordx4
__device__ __forceinline__ void load_panel(f32x4 (&av)[16], const bf16* Ab) {
  const bf16* pg1 = Ab + 2048;
  const bf16* pg2 = Ab + 4096;
  const bf16* pg3 = Ab + 6144;
#define LD4(i, p, OFF) asm volatile("global_load_dwordx4 %0, %1, off offset:" OFF " sc0 sc1" : "=v"(av[i]) : "v"(p))
  LD4(0,Ab,"0");  LD4(1,Ab,"1024");  LD4(2,Ab,"2048");  LD4(3,Ab,"3072");
  LD4(4,pg1,"0"); LD4(5,pg1,"1024"); LD4(6,pg1,"2048"); LD4(7,pg1,"3072");
  LD4(8,pg2,"0"); LD4(9,pg2,"1024"); LD4(10,pg2,"2048"); LD4(11,pg2,"3072");
  LD4(12,pg3,"0"); LD4(13,pg3,"1024"); LD4(14,pg3,"2048"); LD4(15,pg3,"3072");
#undef LD4
}

// ---------------- xp0 = emb[tokens] @ Wx0 + b0  (bf16 MFMA, K padded 100->128) ----------------
__global__ __launch_bounds__(256) void xp0_kernel(const int* __restrict__ tokens,
                                                  const float* __restrict__ emb,
                                                  const float* __restrict__ Wx0,
                                                  const float* __restrict__ b0) {
  __shared__ bf16 A[64 * 128];
  __shared__ int toks[64];
  const int mt = blockIdx.x;
  const int nt = blockIdx.y;
  const int tid = threadIdx.x, lane = tid & 63, wv = tid >> 6;

  if (tid < 64) {
    int R = mt * 64 + tid;
    int tok = 0;
    if (R < MROWS) { int s = R / 250; int b = R - s * 250; tok = tokens[b * SEQ + s]; }
    toks[tid] = tok;
  }
  __syncthreads();
  for (int idx = tid; idx < 64 * 128; idx += 256) {
    int r = idx >> 7, k = idx & 127;
    float v = (k < EMBD) ? emb[(size_t)toks[r] * EMBD + k] : 0.f;
    unsigned off = (unsigned)(r * 256 + k * 2);
    off ^= (unsigned)((r & 7) << 4);
    *(bf16*)((char*)A + off) = (bf16)v;
  }

  const int colb = nt * 256 + (wv << 6) + (lane & 31);
  bf16x8 Bf[2][8];
  #pragma unroll
  for (int nf = 0; nf < 2; ++nf) {
    #pragma unroll
    for (int kk = 0; kk < 8; ++kk) {
      const int kb = (kk << 4) + ((lane >> 5) << 3);
      bf16x8 f;
      #pragma unroll
      for (int j = 0; j < 8; ++j) {
        int k = kb + j;
        f[j] = (bf16)((k < EMBD) ? Wx0[(size_t)k * UNITS + colb + (nf << 5)] : 0.f);
      }
      Bf[nf][kk] = f;
    }
  }
  __syncthreads();

  f32x16 acc00 = F32X16_ZERO, acc01 = F32X16_ZERO, acc10 = F32X16_ZERO, acc11 = F32X16_ZERO;
  #pragma unroll
  for (int kk = 0; kk < 8; ++kk) {
    #pragma unroll
    for (int mf = 0; mf < 2; ++mf) {
      int row = (mf << 5) + (lane & 31);
      unsigned off = (unsigned)(row * 256 + ((kk << 4) + ((lane >> 5) << 3)) * 2);
      off ^= (unsigned)((row & 7) << 4);
      bf16x8 a = *(const bf16x8*)((const char*)A + off);
      if (mf == 0) { acc00 = MFMA32(a, Bf[0][kk], acc00); acc01 = MFMA32(a, Bf[1][kk], acc01); }
      else         { acc10 = MFMA32(a, Bf[0][kk], acc10); acc11 = MFMA32(a, Bf[1][kk], acc11); }
    }
  }

  const float bb0 = b0[colb], bb1 = b0[colb + 32];
  #pragma unroll
  for (int mf = 0; mf < 2; ++mf) {
    #pragma unroll
    for (int nf = 0; nf < 2; ++nf) {
      #pragma unroll
      for (int reg = 0; reg < 16; ++reg) {
        int r32 = (mf << 5) + ((lane >> 5) << 2) + (reg & 3) + ((reg >> 2) << 3);
        int R = mt * 64 + r32;
        if (R < MROWS) {
          float v = (mf == 0 ? (nf == 0 ? acc00[reg] : acc01[reg])
                             : (nf == 0 ? acc10[reg] : acc11[reg])) + (nf ? bb1 : bb0);
          g_xp0[(size_t)R * UNITS + nt * 256 + (wv << 6) + (nf << 5) + (lane & 31)] = (bf16)v;
        }
      }
    }
  }
}

// ---------------- persistent scan: 64 fused L0F blocks (Wh0 + Wx1) + 64 BK blocks (Wh1 + P) ----------------
__global__ __launch_bounds__(512, 1) void rnn_persistent(const float* __restrict__ Wh0,
                                                         const float* __restrict__ Wx1,
                                                         const float* __restrict__ Wh1,
                                                         const float* __restrict__ b1) {
  const int bx = blockIdx.x;
  const int role = bx >> 6;            // 0: L0F (h0 + P), 1: BK (h1)
  const int tile = bx & 63;
  const int m = tile >> 4, n = tile & 15;
  const int tid = threadIdx.x;
  const int lane = tid & 63, w = tid >> 6;
  const int mt = w & 1, kq = w >> 1;                 // GEMM role: M-half, K-quarter
  const int mt_c = w & 1, nf_c = (w >> 1) & 1, rs = w >> 2;  // combiner role

  __shared__ bf16 red[16][32][64];     // 64KB: slots [mat*8 + kq*2 + mt][nf*16+reg][lane]

  // ---- one-time: weight fragments to registers ----
  const int colA = n * 64 + (lane & 31);
  const int kb = kq * 256 + ((lane >> 5) << 3);
  bf16x8 BfA[2][16], BfB[2][16];
  {
    const float* WA = role ? Wh1 : Wh0;
    #pragma unroll
    for (int nf = 0; nf < 2; ++nf)
      #pragma unroll
      for (int kk = 0; kk < 16; ++kk) {
        const float* s = WA + (size_t)(kb + kk * 16) * UNITS + colA + nf * 32;
        bf16x8 f;
        #pragma unroll
        for (int j = 0; j < 8; ++j) f[j] = (bf16)s[(size_t)j * UNITS];
        BfA[nf][kk] = f;
      }
    if (role == 0) {
      #pragma unroll
      for (int nf = 0; nf < 2; ++nf)
        #pragma unroll
        for (int kk = 0; kk < 16; ++kk) {
          const float* s = Wx1 + (size_t)(kb + kk * 16) * UNITS + colA + nf * 32;
          bf16x8 f;
          #pragma unroll
          for (int j = 0; j < 8; ++j) f[j] = (bf16)s[(size_t)j * UNITS];
          BfB[nf][kk] = f;
        }
    }
  }
  const int r32c = ((lane >> 5) << 2) + (rs << 4);   // row base; j adds (j&3)+8*(j>>2)
  const int Cc = (nf_c << 5) + (lane & 31);          // local col
  float b1v = 0.f;
  if (role == 1) b1v = b1[n * 64 + Cc];

  // A-panel base (elements, tiled layout)
  const size_t abase = ((size_t)((m * 2 + mt) * 128 + kq * 32 + (lane >> 5))) * 256 + (size_t)(lane & 31) * 8;
  // combiner h-store base (tiled) and P base (plain 64x64)
  const size_t hsb = ((size_t)((m * 2 + mt_c) * 128 + (Cc >> 3))) * 256 + (size_t)r32c * 8 + (Cc & 7);
  const int    psb = (mt_c * 32 + r32c) * 64 + Cc;

  for (int t = role; t <= SEQ; ++t) {
    if (role == 0) {
      const bool hasA = (t >= 1);
      const bool hasH = (t < SEQ);
      // prefetch xp0 fragment (plain cached loads, independent of flags)
      unsigned short xv[8];
      if (hasH) {
        const size_t xr = (size_t)(t * BAT + m * 64 + mt_c * 32 + r32c) * UNITS + n * 64 + Cc;
        #pragma unroll
        for (int j = 0; j < 8; ++j)
          xv[j] = __builtin_bit_cast(unsigned short,
                    g_xp0[xr + (size_t)((j & 3) + ((j >> 2) << 3)) * UNITS]);
      }
      // polls (lane0 per wave; wave sleeps with it)
      if (lane == 0) {
        if (t >= 1) while (aload(&g_fh0[m]) < 16u * (unsigned)t) __builtin_amdgcn_s_sleep(1);
        if (t >= 3) while (aload(&g_fPc[tile]) < (unsigned)(t - 2)) __builtin_amdgcn_s_sleep(1);
      }
      asm volatile("" ::: "memory");

      f32x16 aH0 = F32X16_ZERO, aH1 = F32X16_ZERO, aP0 = F32X16_ZERO, aP1 = F32X16_ZERO;
      if (hasA) {
        f32x4 av[16];
        load_panel(av, g_h0[(t + 1) & 1] + abase);   // A = h0[t-1]
        asm volatile("s_waitcnt vmcnt(0)" ::: "memory");
        __builtin_amdgcn_sched_barrier(0);
        #pragma unroll
        for (int kk = 0; kk < 16; ++kk) {
          bf16x8 a = __builtin_bit_cast(bf16x8, av[kk]);
          aH0 = MFMA32(a, BfA[0][kk], aH0);
          aH1 = MFMA32(a, BfA[1][kk], aH1);
          aP0 = MFMA32(a, BfB[0][kk], aP0);
          aP1 = MFMA32(a, BfB[1][kk], aP1);
        }
      }
      {
        const int s0 = kq * 2 + mt, s1 = 8 + s0;
        #pragma unroll
        for (int r = 0; r < 16; ++r) {
          red[s0][r][lane]      = (bf16)aH0[r];
          red[s0][16 + r][lane] = (bf16)aH1[r];
          red[s1][r][lane]      = (bf16)aP0[r];
          red[s1][16 + r][lane] = (bf16)aP1[r];
        }
      }
      __syncthreads();
      if (hasH) {
        bf16* hb = g_h0[t & 1] + hsb;
#define HSTEP(J, HOFF) { \
        const int idx = (nf_c << 4) + (rs << 3) + J; \
        float f = (float)red[mt_c][idx][lane] + (float)red[2 + mt_c][idx][lane] \
                + (float)red[4 + mt_c][idx][lane] + (float)red[6 + mt_c][idx][lane]; \
        f += __builtin_bit_cast(float, ((unsigned)xv[J]) << 16); \
        f = tanh_fast(f); \
        unsigned hv = (unsigned)__builtin_bit_cast(unsigned short, (bf16)f); \
        asm volatile("global_store_short %0, %1, off offset:" HOFF " sc0 sc1" :: "v"(hb), "v"(hv) : "memory"); }
        HSTEP(0,"0") HSTEP(1,"16") HSTEP(2,"32") HSTEP(3,"48")
        HSTEP(4,"128") HSTEP(5,"144") HSTEP(6,"160") HSTEP(7,"176")
#undef HSTEP
      }
      if (t >= 1) {
        float* pb = &g_P[tile][(t - 1) & 1][psb];
#define PSTEP(J, POFF) { \
        const int idx = (nf_c << 4) + (rs << 3) + J; \
        float f = (float)red[8 + mt_c][idx][lane] + (float)red[10 + mt_c][idx][lane] \
                + (float)red[12 + mt_c][idx][lane] + (float)red[14 + mt_c][idx][lane]; \
        asm volatile("global_store_dword %0, %1, off offset:" POFF " sc0 sc1" :: "v"(pb), "v"(f) : "memory"); }
        PSTEP(0,"0") PSTEP(1,"256") PSTEP(2,"512") PSTEP(3,"768")
        PSTEP(4,"2048") PSTEP(5,"2304") PSTEP(6,"2560") PSTEP(7,"2816")
#undef PSTEP
      }
      asm volatile("s_waitcnt vmcnt(0)" ::: "memory");
      __syncthreads();
      if (tid == 0) {
        if (hasH) aadd(&g_fh0[m], 1u);
        if (t >= 1) astore(&g_fP[tile], (unsigned)t);
      }
    } else {
      // ---- BK: h1[t-1] = tanh(h1[t-2]@Wh1 + P[t-1] + b1) ----
      if (lane == 0) {
        while (aload(&g_fP[tile]) < (unsigned)t) __builtin_amdgcn_s_sleep(1);
        if (t >= 2) while (aload(&g_fh1[m]) < 16u * (unsigned)(t - 1)) __builtin_amdgcn_s_sleep(1);
      }
      asm volatile("" ::: "memory");
      // P loads (combiner fragment, bypass)
      const float* pb = &g_P[tile][(t - 1) & 1][psb];
      float pv[8];
#define PL(J, POFF) asm volatile("global_load_dword %0, %1, off offset:" POFF " sc0 sc1" : "=v"(pv[J]) : "v"(pb));
      PL(0,"0") PL(1,"256") PL(2,"512") PL(3,"768")
      PL(4,"2048") PL(5,"2304") PL(6,"2560") PL(7,"2816")
#undef PL
      f32x16 a0 = F32X16_ZERO, a1 = F32X16_ZERO;
      f32x4 av[16];
      if (t >= 2) load_panel(av, g_h1[t & 1] + abase);   // A = h1[t-2]
      asm volatile("s_waitcnt vmcnt(0)" ::: "memory");
      __builtin_amdgcn_sched_barrier(0);
      if (t >= 2) {
        #pragma unroll
        for (int kk = 0; kk < 16; ++kk) {
          bf16x8 a = __builtin_bit_cast(bf16x8, av[kk]);
          a0 = MFMA32(a, BfA[0][kk], a0);
          a1 = MFMA32(a, BfA[1][kk], a1);
        }
      }
      {
        const int s0 = kq * 2 + mt;
        #pragma unroll
        for (int r = 0; r < 16; ++r) {
          red[s0][r][lane]      = (bf16)a0[r];
          red[s0][16 + r][lane] = (bf16)a1[r];
        }
      }
      __syncthreads();
      if (tid == 0) astore(&g_fPc[tile], (unsigned)t);   // P + h-panel consumed
      {
        bf16* hb = g_h1[(t + 1) & 1] + hsb;
#define BSTEP(J, HOFF) { \
        const int idx = (nf_c << 4) + (rs << 3) + J; \
        float f = (float)red[mt_c][idx][lane] + (float)red[2 + mt_c][idx][lane] \
                + (float)red[4 + mt_c][idx][lane] + (float)red[6 + mt_c][idx][lane]; \
        f += pv[J] + b1v; \
        f = tanh_fast(f); \
        unsigned hv = (unsigned)__builtin_bit_cast(unsigned short, (bf16)f); \
        asm volatile("global_store_short %0, %1, off offset:" HOFF " sc0 sc1" :: "v"(hb), "v"(hv) : "memory"); }
        BSTEP(0,"0") BSTEP(1,"16") BSTEP(2,"32") BSTEP(3,"48")
        BSTEP(4,"128") BSTEP(5,"144") BSTEP(6,"160") BSTEP(7,"176")
#undef BSTEP
      }
      asm volatile("s_waitcnt vmcnt(0)" ::: "memory");
      __syncthreads();
      if (tid == 0) aadd(&g_fh1[m], 1u);
    }
  }
}

// ---------------- logits + flag reset for next graph replay ----------------
__global__ __launch_bounds__(64) void logits_kernel(const float* __restrict__ Wo,
                                                    const float* __restrict__ bo,
                                                    float* __restrict__ out) {
  const int b = blockIdx.x, lane = threadIdx.x;
  if (b == 0) {
    g_fP[lane] = 0; g_fPc[lane] = 0;
    if (lane < 4) { g_fh0[lane] = 0; g_fh1[lane] = 0; }
  }
  const bf16* h = g_h1[1];   // h1[299]
  const size_t base = ((size_t)((b >> 5) * 128 + lane * 2)) * 256 + (size_t)(b & 31) * 8;
  bf16x8 v0 = *(const bf16x8*)&h[base];
  bf16x8 v1 = *(const bf16x8*)&h[base + 256];
  float s = 0.f;
  #pragma unroll
  for (int j = 0; j < 8; ++j) {
    s += (float)v0[j] * Wo[lane * 16 + j];
    s += (float)v1[j] * Wo[lane * 16 + 8 + j];
  }
  #pragma unroll
  for (int off = 32; off; off >>= 1) s += __shfl_xor(s, off, 64);
  if (lane == 0) out[b] = 1.f / (1.f + __expf(-(s + bo[0])));
}

extern "C" void kernel_launch(void* const* d_in, const int* in_sizes, int n_in,
                              void* d_out, int out_size, void* d_ws, size_t ws_size,
                              hipStream_t stream) {
  const int*   tokens = (const int*)  d_in[0];
  const float* emb    = (const float*)d_in[1];
  const float* Wx0    = (const float*)d_in[2];
  const float* Wh0    = (const float*)d_in[3];
  const float* b0     = (const float*)d_in[4];
  const float* Wx1    = (const float*)d_in[5];
  const float* Wh1    = (const float*)d_in[6];
  const float* b1     = (const float*)d_in[7];
  const float* Wo     = (const float*)d_in[8];
  const float* bo     = (const float*)d_in[9];
  float* out = (float*)d_out;

  dim3 gx((MROWS + 63) / 64, 4);
  xp0_kernel<<<gx, 256, 0, stream>>>(tokens, emb, Wx0, b0);

  rnn_persistent<<<128, 512, 0, stream>>>(Wh0, Wx1, Wh1, b1);

  logits_kernel<<<BAT, 64, 0, stream>>>(Wo, bo, out);
}

// Round 4
// 3697.609 us; speedup vs baseline: 3.3361x; 2.1323x over previous
//
#include <hip/hip_runtime.h>
#include <hip/hip_bf16.h>

#define SEQ 300
#define BAT 250
#define UNITS 1024
#define EMBD 100
#define MROWS (SEQ*BAT)   // 75000, s-major: row = s*250 + b

typedef __bf16 bf16;
typedef __bf16 bf16x8 __attribute__((ext_vector_type(8)));
typedef float  f32x4  __attribute__((ext_vector_type(4)));
typedef float  f32x16 __attribute__((ext_vector_type(16)));

#define MFMA32(a,b,c) __builtin_amdgcn_mfma_f32_32x32x16_bf16(a,b,c,0,0,0)
#define F32X16_ZERO {0.f,0.f,0.f,0.f,0.f,0.f,0.f,0.f,0.f,0.f,0.f,0.f,0.f,0.f,0.f,0.f}

// ---- device globals ----
// xp0 plain row-major [R][1024]; h-state TILED: elem(r,u) -> ((r>>5)*128 + (u>>3))*256 + (r&31)*8 + (u&7)
__device__ __align__(16) bf16  g_xp0[(size_t)MROWS*UNITS + 8192];
__device__ __align__(16) bf16  g_h0[2][256*1024];
__device__ __align__(16) bf16  g_h1[2][256*1024];
__device__ __align__(16) float g_P[64][2][64*64];   // [tile][buf][r][c] f32
__device__ unsigned g_fh0[4], g_fh1[4], g_fFR[4], g_fP[64], g_fPc[64];

__device__ __forceinline__ float tanh_fast(float x) {
  float e = __expf(2.f * x);
  return 1.f - 2.f / (e + 1.f);
}
__device__ __forceinline__ unsigned aload(unsigned* p) {
  return __hip_atomic_load(p, __ATOMIC_RELAXED, __HIP_MEMORY_SCOPE_AGENT);
}
__device__ __forceinline__ void aadd(unsigned* p, unsigned v) {
  __hip_atomic_fetch_add(p, v, __ATOMIC_RELAXED, __HIP_MEMORY_SCOPE_AGENT);
}
__device__ __forceinline__ void astore(unsigned* p, unsigned v) {
  __hip_atomic_store(p, v, __ATOMIC_RELAXED, __HIP_MEMORY_SCOPE_AGENT);
}

// coalesced cache-bypass panel load: 16 x 1KB-per-wave contiguous dwordx4
__device__ __forceinline__ void load_panel(f32x4 (&av)[16], const bf16* Ab) {
  const bf16* pg1 = Ab + 2048;
  const bf16* pg2 = Ab + 4096;
  const bf16* pg3 = Ab + 6144;
#define LD4(i, p, OFF) asm volatile("global_load_dwordx4 %0, %1, off offset:" OFF " sc0 sc1" : "=v"(av[i]) : "v"(p))
  LD4(0,Ab,"0");  LD4(1,Ab,"1024");  LD4(2,Ab,"2048");  LD4(3,Ab,"3072");
  LD4(4,pg1,"0"); LD4(5,pg1,"1024"); LD4(6,pg1,"2048"); LD4(7,pg1,"3072");
  LD4(8,pg2,"0"); LD4(9,pg2,"1024"); LD4(10,pg2,"2048"); LD4(11,pg2,"3072");
  LD4(12,pg3,"0"); LD4(13,pg3,"1024"); LD4(14,pg3,"2048"); LD4(15,pg3,"3072");
#undef LD4
}

// ---------------- xp0 = emb[tokens] @ Wx0 + b0  (bf16 MFMA, K padded 100->128) ----------------
__global__ __launch_bounds__(256) void xp0_kernel(const int* __restrict__ tokens,
                                                  const float* __restrict__ emb,
                                                  const float* __restrict__ Wx0,
                                                  const float* __restrict__ b0) {
  __shared__ bf16 A[64 * 128];
  __shared__ int toks[64];
  const int mt = blockIdx.x;
  const int nt = blockIdx.y;
  const int tid = threadIdx.x, lane = tid & 63, wv = tid >> 6;

  if (tid < 64) {
    int R = mt * 64 + tid;
    int tok = 0;
    if (R < MROWS) { int s = R / 250; int b = R - s * 250; tok = tokens[b * SEQ + s]; }
    toks[tid] = tok;
  }
  __syncthreads();
  for (int idx = tid; idx < 64 * 128; idx += 256) {
    int r = idx >> 7, k = idx & 127;
    float v = (k < EMBD) ? emb[(size_t)toks[r] * EMBD + k] : 0.f;
    unsigned off = (unsigned)(r * 256 + k * 2);
    off ^= (unsigned)((r & 7) << 4);
    *(bf16*)((char*)A + off) = (bf16)v;
  }

  const int colb = nt * 256 + (wv << 6) + (lane & 31);
  bf16x8 Bf[2][8];
  #pragma unroll
  for (int nf = 0; nf < 2; ++nf) {
    #pragma unroll
    for (int kk = 0; kk < 8; ++kk) {
      const int kb = (kk << 4) + ((lane >> 5) << 3);
      bf16x8 f;
      #pragma unroll
      for (int j = 0; j < 8; ++j) {
        int k = kb + j;
        f[j] = (bf16)((k < EMBD) ? Wx0[(size_t)k * UNITS + colb + (nf << 5)] : 0.f);
      }
      Bf[nf][kk] = f;
    }
  }
  __syncthreads();

  f32x16 acc00 = F32X16_ZERO, acc01 = F32X16_ZERO, acc10 = F32X16_ZERO, acc11 = F32X16_ZERO;
  #pragma unroll
  for (int kk = 0; kk < 8; ++kk) {
    #pragma unroll
    for (int mf = 0; mf < 2; ++mf) {
      int row = (mf << 5) + (lane & 31);
      unsigned off = (unsigned)(row * 256 + ((kk << 4) + ((lane >> 5) << 3)) * 2);
      off ^= (unsigned)((row & 7) << 4);
      bf16x8 a = *(const bf16x8*)((const char*)A + off);
      if (mf == 0) { acc00 = MFMA32(a, Bf[0][kk], acc00); acc01 = MFMA32(a, Bf[1][kk], acc01); }
      else         { acc10 = MFMA32(a, Bf[0][kk], acc10); acc11 = MFMA32(a, Bf[1][kk], acc11); }
    }
  }

  const float bb0 = b0[colb], bb1 = b0[colb + 32];
  #pragma unroll
  for (int mf = 0; mf < 2; ++mf) {
    #pragma unroll
    for (int nf = 0; nf < 2; ++nf) {
      #pragma unroll
      for (int reg = 0; reg < 16; ++reg) {
        int r32 = (mf << 5) + ((lane >> 5) << 2) + (reg & 3) + ((reg >> 2) << 3);
        int R = mt * 64 + r32;
        if (R < MROWS) {
          float v = (mf == 0 ? (nf == 0 ? acc00[reg] : acc01[reg])
                             : (nf == 0 ? acc10[reg] : acc11[reg])) + (nf ? bb1 : bb0);
          g_xp0[(size_t)R * UNITS + nt * 256 + (wv << 6) + (nf << 5) + (lane & 31)] = (bf16)v;
        }
      }
    }
  }
}

// ---------------- persistent scan: 3 roles x 64 tiles = 192 blocks, one weight matrix per block ----------------
__global__ __launch_bounds__(512, 2) void rnn_persistent(const float* __restrict__ Wh0,
                                                         const float* __restrict__ Wx1,
                                                         const float* __restrict__ Wh1,
                                                         const float* __restrict__ b1) {
  const int bx = blockIdx.x;
  const int role = bx >> 6;            // 0: L0 (Wh0), 1: FR (Wx1->P), 2: BK (Wh1+P)
  const int tile = bx & 63;
  const int m = tile >> 4, n = tile & 15;
  const int tid = threadIdx.x;
  const int lane = tid & 63, w = tid >> 6;
  const int mt = w & 1, kq = w >> 1;   // GEMM wave role: M-half (32 rows), K-quarter (256)

  // combiner role: thread -> (row rp in tile, col-block cblk of 8 u)
  const int cblk = tid >> 6, rp = tid & 63;
  const int mtc = rp >> 5, rpp = rp & 31;
  const int hi = (rpp >> 2) & 1;
  const int idx = ((cblk >> 2) << 4) + (rpp & 3) + ((rpp >> 3) << 2);
  const int entry = (hi << 5) + ((cblk & 3) << 3);

  __shared__ bf16 red[8][32][68];      // [kq*2+mt][nf*16+reg][lane], pad 68 -> ~2-way banks

  // ---- one-time: weight fragments into registers (128 VGPRs) ----
  const float* W = (role == 0) ? Wh0 : (role == 1) ? Wx1 : Wh1;
  bf16x8 Bf[2][16];
  {
    const int colA = n * 64 + (lane & 31);
    const int kb = (kq << 8) + ((lane >> 5) << 3);
    #pragma unroll
    for (int nf = 0; nf < 2; ++nf)
      #pragma unroll
      for (int kk = 0; kk < 16; ++kk) {
        const float* s = W + (size_t)(kb + (kk << 4)) * UNITS + colA + (nf << 5);
        bf16x8 f;
        #pragma unroll
        for (int j = 0; j < 8; ++j) f[j] = (bf16)s[(size_t)j * UNITS];
        Bf[nf][kk] = f;
      }
  }
  float b1v[8];
  if (role == 2) {
    #pragma unroll
    for (int j = 0; j < 8; ++j) b1v[j] = b1[n * 64 + (cblk << 3) + j];
  }

  // A-panel base (tiled layout, per GEMM wave)
  const size_t abase = ((size_t)((m * 2 + mt) * 128 + kq * 32 + (lane >> 5))) * 256 + (size_t)(lane & 31) * 8;
  // combiner store base in tiled h layout: row R = m*64+rp, u-block = n*8+cblk
  const size_t hsb = ((size_t)((m * 2 + mtc) * 128 + n * 8 + cblk)) * 256 + (size_t)rpp * 8;
  const int    psb = rp * 64 + (cblk << 3);          // P [r][c] f32

  for (int t = 0; t <= SEQ; ++t) {
    if (role == 0) {
      if (t >= SEQ) continue;
      // prefetch xp0 fragment: one dwordx4 (8 bf16), contiguous per thread
      bf16x8 xv = *(const bf16x8*)&g_xp0[(size_t)(t * BAT + m * 64 + rp) * UNITS + n * 64 + (cblk << 3)];
      if (tid == 0) {
        if (t >= 1) while (aload(&g_fh0[m]) < 16u * (unsigned)t) __builtin_amdgcn_s_sleep(2);
        if (t >= 2) while (aload(&g_fFR[m]) < 16u * (unsigned)(t - 1)) __builtin_amdgcn_s_sleep(2);
      }
      __syncthreads();

      f32x16 acc0 = F32X16_ZERO, acc1 = F32X16_ZERO;
      if (t >= 1) {
        f32x4 av[16];
        load_panel(av, g_h0[(t + 1) & 1] + abase);
        asm volatile("s_waitcnt vmcnt(0)" ::: "memory");
        __builtin_amdgcn_sched_barrier(0);
        #pragma unroll
        for (int kk = 0; kk < 16; ++kk) {
          bf16x8 a = __builtin_bit_cast(bf16x8, av[kk]);
          acc0 = MFMA32(a, Bf[0][kk], acc0);
          acc1 = MFMA32(a, Bf[1][kk], acc1);
        }
      }
      {
        const int s0 = kq * 2 + mt;
        #pragma unroll
        for (int r = 0; r < 16; ++r) {
          red[s0][r][lane]      = (bf16)acc0[r];
          red[s0][16 + r][lane] = (bf16)acc1[r];
        }
      }
      __syncthreads();
      {
        float s[8];
        #pragma unroll
        for (int j = 0; j < 8; ++j) s[j] = (float)xv[j];
        #pragma unroll
        for (int k4 = 0; k4 < 4; ++k4) {
          bf16x8 v = *(const bf16x8*)&red[k4 * 2 + mtc][idx][entry];
          #pragma unroll
          for (int j = 0; j < 8; ++j) s[j] += (float)v[j];
        }
        union { bf16 h[8]; f32x4 v; } o;
        #pragma unroll
        for (int j = 0; j < 8; ++j) o.h[j] = (bf16)tanh_fast(s[j]);
        bf16* hb = g_h0[t & 1] + hsb;
        asm volatile("global_store_dwordx4 %0, %1, off sc0 sc1" :: "v"(hb), "v"(o.v) : "memory");
      }
      asm volatile("s_waitcnt vmcnt(0)" ::: "memory");
      __syncthreads();
      if (tid == 0) aadd(&g_fh0[m], 1u);
    } else if (role == 1) {
      if (t < 1) continue;
      if (tid == 0) {
        while (aload(&g_fh0[m]) < 16u * (unsigned)t) __builtin_amdgcn_s_sleep(2);
        if (t >= 3) while (aload(&g_fPc[tile]) < (unsigned)(t - 2)) __builtin_amdgcn_s_sleep(2);
      }
      __syncthreads();

      f32x16 acc0 = F32X16_ZERO, acc1 = F32X16_ZERO;
      {
        f32x4 av[16];
        load_panel(av, g_h0[(t + 1) & 1] + abase);
        asm volatile("s_waitcnt vmcnt(0)" ::: "memory");
        __builtin_amdgcn_sched_barrier(0);
        #pragma unroll
        for (int kk = 0; kk < 16; ++kk) {
          bf16x8 a = __builtin_bit_cast(bf16x8, av[kk]);
          acc0 = MFMA32(a, Bf[0][kk], acc0);
          acc1 = MFMA32(a, Bf[1][kk], acc1);
        }
      }
      {
        const int s0 = kq * 2 + mt;
        #pragma unroll
        for (int r = 0; r < 16; ++r) {
          red[s0][r][lane]      = (bf16)acc0[r];
          red[s0][16 + r][lane] = (bf16)acc1[r];
        }
      }
      __syncthreads();
      {
        float s[8];
        #pragma unroll
        for (int j = 0; j < 8; ++j) s[j] = 0.f;
        #pragma unroll
        for (int k4 = 0; k4 < 4; ++k4) {
          bf16x8 v = *(const bf16x8*)&red[k4 * 2 + mtc][idx][entry];
          #pragma unroll
          for (int j = 0; j < 8; ++j) s[j] += (float)v[j];
        }
        float* pb = &g_P[tile][(t - 1) & 1][psb];
        f32x4 lo = {s[0], s[1], s[2], s[3]}, hic = {s[4], s[5], s[6], s[7]};
        asm volatile("global_store_dwordx4 %0, %1, off sc0 sc1" :: "v"(pb), "v"(lo) : "memory");
        asm volatile("global_store_dwordx4 %0, %1, off offset:16 sc0 sc1" :: "v"(pb), "v"(hic) : "memory");
      }
      asm volatile("s_waitcnt vmcnt(0)" ::: "memory");
      __syncthreads();
      if (tid == 0) { astore(&g_fP[tile], (unsigned)t); aadd(&g_fFR[m], 1u); }
    } else {
      if (t < 1) continue;
      if (tid == 0) {
        while (aload(&g_fP[tile]) < (unsigned)t) __builtin_amdgcn_s_sleep(2);
        if (t >= 2) while (aload(&g_fh1[m]) < 16u * (unsigned)(t - 1)) __builtin_amdgcn_s_sleep(2);
      }
      __syncthreads();

      // P prefetch (combiner fragment)
      f32x4 pv0, pv1;
      {
        const float* pb = &g_P[tile][(t - 1) & 1][psb];
        asm volatile("global_load_dwordx4 %0, %1, off sc0 sc1" : "=v"(pv0) : "v"(pb));
        asm volatile("global_load_dwordx4 %0, %1, off offset:16 sc0 sc1" : "=v"(pv1) : "v"(pb));
      }
      f32x16 acc0 = F32X16_ZERO, acc1 = F32X16_ZERO;
      if (t >= 2) {
        f32x4 av[16];
        load_panel(av, g_h1[t & 1] + abase);
        asm volatile("s_waitcnt vmcnt(0)" ::: "memory");
        __builtin_amdgcn_sched_barrier(0);
        #pragma unroll
        for (int kk = 0; kk < 16; ++kk) {
          bf16x8 a = __builtin_bit_cast(bf16x8, av[kk]);
          acc0 = MFMA32(a, Bf[0][kk], acc0);
          acc1 = MFMA32(a, Bf[1][kk], acc1);
        }
      } else {
        asm volatile("s_waitcnt vmcnt(0)" ::: "memory");
      }
      {
        const int s0 = kq * 2 + mt;
        #pragma unroll
        for (int r = 0; r < 16; ++r) {
          red[s0][r][lane]      = (bf16)acc0[r];
          red[s0][16 + r][lane] = (bf16)acc1[r];
        }
      }
      __syncthreads();
      {
        float s[8];
        #pragma unroll
        for (int j = 0; j < 4; ++j) { s[j] = pv0[j] + b1v[j]; s[4 + j] = pv1[j] + b1v[4 + j]; }
        #pragma unroll
        for (int k4 = 0; k4 < 4; ++k4) {
          bf16x8 v = *(const bf16x8*)&red[k4 * 2 + mtc][idx][entry];
          #pragma unroll
          for (int j = 0; j < 8; ++j) s[j] += (float)v[j];
        }
        union { bf16 h[8]; f32x4 v; } o;
        #pragma unroll
        for (int j = 0; j < 8; ++j) o.h[j] = (bf16)tanh_fast(s[j]);
        bf16* hb = g_h1[(t + 1) & 1] + hsb;   // h1[t-1]
        asm volatile("global_store_dwordx4 %0, %1, off sc0 sc1" :: "v"(hb), "v"(o.v) : "memory");
      }
      asm volatile("s_waitcnt vmcnt(0)" ::: "memory");
      __syncthreads();
      if (tid == 0) { aadd(&g_fh1[m], 1u); astore(&g_fPc[tile], (unsigned)t); }
    }
  }
}

// ---------------- logits + flag reset for next graph replay ----------------
__global__ __launch_bounds__(64) void logits_kernel(const float* __restrict__ Wo,
                                                    const float* __restrict__ bo,
                                                    float* __restrict__ out) {
  const int b = blockIdx.x, lane = threadIdx.x;
  if (b == 0) {
    g_fP[lane] = 0; g_fPc[lane] = 0;
    if (lane < 4) { g_fh0[lane] = 0; g_fh1[lane] = 0; g_fFR[lane] = 0; }
  }
  const bf16* h = g_h1[1];   // h1[299]
  const size_t base = ((size_t)((b >> 5) * 128 + lane * 2)) * 256 + (size_t)(b & 31) * 8;
  bf16x8 v0 = *(const bf16x8*)&h[base];
  bf16x8 v1 = *(const bf16x8*)&h[base + 256];
  float s = 0.f;
  #pragma unroll
  for (int j = 0; j < 8; ++j) {
    s += (float)v0[j] * Wo[lane * 16 + j];
    s += (float)v1[j] * Wo[lane * 16 + 8 + j];
  }
  #pragma unroll
  for (int off = 32; off; off >>= 1) s += __shfl_xor(s, off, 64);
  if (lane == 0) out[b] = 1.f / (1.f + __expf(-(s + bo[0])));
}

extern "C" void kernel_launch(void* const* d_in, const int* in_sizes, int n_in,
                              void* d_out, int out_size, void* d_ws, size_t ws_size,
                              hipStream_t stream) {
  const int*   tokens = (const int*)  d_in[0];
  const float* emb    = (const float*)d_in[1];
  const float* Wx0    = (const float*)d_in[2];
  const float* Wh0    = (const float*)d_in[3];
  const float* b0     = (const float*)d_in[4];
  const float* Wx1    = (const float*)d_in[5];
  const float* Wh1    = (const float*)d_in[6];
  const float* b1     = (const float*)d_in[7];
  const float* Wo     = (const float*)d_in[8];
  const float* bo     = (const float*)d_in[9];
  float* out = (float*)d_out;

  dim3 gx((MROWS + 63) / 64, 4);
  xp0_kernel<<<gx, 256, 0, stream>>>(tokens, emb, Wx0, b0);

  rnn_persistent<<<192, 512, 0, stream>>>(Wh0, Wx1, Wh1, b1);

  logits_kernel<<<BAT, 64, 0, stream>>>(Wo, bo, out);
}